// Round 5
// baseline (704.421 us; speedup 1.0000x reference)
//
#include <hip/hip_runtime.h>

#define NT 8192      // tokens = B*S
#define DIM 1024     // D
#define FDIM 4096    // F
#define NEXP 8       // experts

typedef __attribute__((ext_vector_type(8))) short bfx8;   // 8 bf16 (4 VGPRs)
typedef __attribute__((ext_vector_type(4))) float fx4;    // MFMA accumulator

__device__ __forceinline__ unsigned short f2bf(float f) {
  union { float f; unsigned u; } v; v.f = f;
  unsigned u = v.u;
  unsigned r = u + 0x7FFFu + ((u >> 16) & 1u);   // round-to-nearest-even
  return (unsigned short)(r >> 16);
}

__device__ __forceinline__ void gload16(const void* g, void* l) {
  __builtin_amdgcn_global_load_lds(
      (const __attribute__((address_space(1))) unsigned int*)g,
      (__attribute__((address_space(3))) unsigned int*)l, 16, 0, 0);
}

// ---------------- zero counters ----------------
__global__ void k_zero(int* __restrict__ counts) {
  if (threadIdx.x < NEXP) counts[threadIdx.x] = 0;
}

// ---------------- routing: argmax affinity + alpha ----------------
__global__ __launch_bounds__(256) void k_routing(
    const float* __restrict__ x, const float* __restrict__ cent,
    int* __restrict__ eid, float* __restrict__ alpha, int* __restrict__ counts)
{
  const int t = blockIdx.x, tid = threadIdx.x;
  const float4 xv = ((const float4*)(x + (size_t)t * DIM))[tid];
  float acc[NEXP];
#pragma unroll
  for (int e = 0; e < NEXP; ++e) {
    const float4 cv = ((const float4*)(cent + (size_t)e * DIM))[tid];
    acc[e] = xv.x * cv.x + xv.y * cv.y + xv.z * cv.z + xv.w * cv.w;
  }
#pragma unroll
  for (int off = 32; off > 0; off >>= 1)
#pragma unroll
    for (int e = 0; e < NEXP; ++e) acc[e] += __shfl_down(acc[e], off);
  __shared__ float part[4][NEXP];
  const int lane = tid & 63, w = tid >> 6;
  if (lane == 0)
#pragma unroll
    for (int e = 0; e < NEXP; ++e) part[w][e] = acc[e];
  __syncthreads();
  if (tid == 0) {
    int best = 0; float bv = -1e30f;
#pragma unroll
    for (int e = 0; e < NEXP; ++e) {
      float v = part[0][e] + part[1][e] + part[2][e] + part[3][e];
      if (v > bv) { bv = v; best = e; }
    }
    eid[t] = best;
    alpha[t] = 1.0f / (1.0f + expf(-bv));
    atomicAdd(&counts[best], 1);
  }
}

// ---------------- exclusive scan of 8 counts ----------------
__global__ void k_scan(const int* __restrict__ counts, int* __restrict__ bs, int* __restrict__ cur) {
  if (threadIdx.x == 0) {
    int s = 0;
    for (int e = 0; e < NEXP; ++e) { bs[e] = s; cur[e] = s; s += counts[e]; }
  }
}

// ---------------- LayerNorm + counting-sort scatter (bf16) ----------------
__global__ __launch_bounds__(256) void k_ln_scatter(
    const float* __restrict__ x, const float* __restrict__ g, const float* __restrict__ b,
    const int* __restrict__ eid, int* __restrict__ cur,
    int* __restrict__ row_tok, unsigned short* __restrict__ xln)
{
  const int t = blockIdx.x, tid = threadIdx.x;
  const float4 xv = ((const float4*)(x + (size_t)t * DIM))[tid];
  float s = xv.x + xv.y + xv.z + xv.w;
  float ss = xv.x * xv.x + xv.y * xv.y + xv.z * xv.z + xv.w * xv.w;
#pragma unroll
  for (int off = 32; off > 0; off >>= 1) { s += __shfl_down(s, off); ss += __shfl_down(ss, off); }
  __shared__ float ps[4], pss[4];
  __shared__ float smu, srstd;
  __shared__ int spos, se;
  const int lane = tid & 63, w = tid >> 6;
  if (lane == 0) { ps[w] = s; pss[w] = ss; }
  __syncthreads();
  if (tid == 0) {
    const float sum = ps[0] + ps[1] + ps[2] + ps[3];
    const float sq  = pss[0] + pss[1] + pss[2] + pss[3];
    const float mu = sum * (1.0f / DIM);
    const float var = sq * (1.0f / DIM) - mu * mu;
    smu = mu; srstd = rsqrtf(var + 1e-5f);
    const int e = eid[t]; se = e;
    const int pos = atomicAdd(&cur[e], 1);
    row_tok[pos] = t;
    spos = pos;
  }
  __syncthreads();
  const float mu = smu, rstd = srstd;
  const int e = se, pos = spos;
  const float4 gv = ((const float4*)(g + (size_t)e * DIM))[tid];
  const float4 bv = ((const float4*)(b + (size_t)e * DIM))[tid];
  ushort4 o;
  o.x = f2bf((xv.x - mu) * rstd * gv.x + bv.x);
  o.y = f2bf((xv.y - mu) * rstd * gv.y + bv.y);
  o.z = f2bf((xv.z - mu) * rstd * gv.z + bv.z);
  o.w = f2bf((xv.w - mu) * rstd * gv.w + bv.w);
  ((ushort4*)(xln + (size_t)pos * DIM))[tid] = o;
}

// ---------------- transpose fp32 [R][C] -> bf16 [C][R], 64x64 tiles ----------------
// v3: coalesced both sides (dst: 128B contiguous per 8 lanes), pad-65 LDS
// (read banks (r+c) mod 32 -> 2-way, free).
__global__ __launch_bounds__(256) void k_transpose(
    const float* __restrict__ in, unsigned short* __restrict__ outT, int R, int C)
{
  __shared__ float T[64 * 65];
  const int e = blockIdx.z;
  const float* src = in + (size_t)e * R * C;
  unsigned short* dst = outT + (size_t)e * R * C;
  const int r0 = blockIdx.y * 64, c0 = blockIdx.x * 64;
  const int t = threadIdx.x;
  const int ry = t >> 4, c4 = (t & 15) * 4;
#pragma unroll
  for (int i = 0; i < 4; ++i) {
    const int r = ry + i * 16;
    const float4 v = *(const float4*)(src + (size_t)(r0 + r) * C + c0 + c4);
    T[r * 65 + c4 + 0] = v.x;
    T[r * 65 + c4 + 1] = v.y;
    T[r * 65 + c4 + 2] = v.z;
    T[r * 65 + c4 + 3] = v.w;
  }
  __syncthreads();
  const int q = t & 7, ny = t >> 3;
#pragma unroll
  for (int i = 0; i < 2; ++i) {
    const int n = ny + i * 32;
    unsigned short o[8];
#pragma unroll
    for (int u = 0; u < 8; ++u) o[u] = f2bf(T[(q * 8 + u) * 65 + n]);
    *(uint4*)(dst + (size_t)(c0 + n) * R + r0 + q * 8) = *(const uint4*)o;
  }
}

// ---------------- grouped MFMA GEMM, 256xBN tile, BK=64, 8 waves, 8-phase ----------------
// K-half ring schedule: 4 LDS slots per operand hold 32-k halves of 2 tiles.
// Phases p1..p8 consume slots 0..3 (2 phases each: M-half 0/1, 16 MFMA/phase);
// each phase stages the just-freed slot's next occupant (A odd, B even phases).
// Counted vmcnt(VW) at phases 4 & 8 only (never 0). Raw s_barrier pairs.
// Grid 1D: expert = bid&7 (== XCD), then n-panel, m fastest (weights L2-resident).
template<int K, int N, int BN, bool FIRST>
__global__ __launch_bounds__(512, 2) void k_gemm(
    const unsigned short* __restrict__ A,
    const unsigned short* __restrict__ Bt,
    const float* __restrict__ bias,
    const int* __restrict__ bs, const int* __restrict__ counts,
    unsigned short* __restrict__ Hout,
    const int* __restrict__ row_tok, const float* __restrict__ alpha,
    const float* __restrict__ xin, float* __restrict__ out)
{
  constexpr int NR = BN / 64;       // per-wave n reps (GEMM1: 4, GEMM2: 2)
  constexpr int GB = BN / 128;      // gloads per B half-stage (2 or 1)
  constexpr int NTILE = K / 64;     // K tiles
  constexpr int MBLK = NT / 256;

  const int bid = blockIdx.x;
  const int e = bid & 7;
  const int l = bid >> 3;
  const int m0 = (l % MBLK) * 256;  // m fastest
  const int n0 = (l / MBLK) * BN;

  const int cnt = counts[e];
  if (m0 >= cnt) return;
  const int rbase = bs[e];

  __shared__ unsigned short sA[4][256 * 32];
  __shared__ unsigned short sB[4][BN * 32];

  const int tid = threadIdx.x;
  const int lane = tid & 63, wv = tid >> 6;
  const int wm = wv >> 2, wn = wv & 3;
  const int lr = lane & 15, lg = lane >> 4;

  fx4 acc[8][NR] = {};

  const unsigned short* Bte = Bt + (size_t)e * N * K;

  const unsigned short* aP[2];
#pragma unroll
  for (int i = 0; i < 2; ++i) {
    const int c = i * 512 + tid;
    int ar = rbase + m0 + (c >> 2);
    ar = ar < NT ? ar : NT - 1;       // clamp: pad rows masked in epilogue
    aP[i] = A + (size_t)ar * K + (c & 3) * 8;
  }
  const unsigned short* bP[2];
#pragma unroll
  for (int i = 0; i < GB; ++i) {
    const int c = i * 512 + tid;
    bP[i] = Bte + (size_t)(n0 + (c >> 2)) * K + (c & 3) * 8;
  }

#define SGA(s, t, kh) if ((t) < NTILE) {                              \
    gload16(aP[0] + (t) * 64 + (kh) * 32, &sA[s][wv * 512]);          \
    gload16(aP[1] + (t) * 64 + (kh) * 32, &sA[s][4096 + wv * 512]); }
#define SGB(s, t, kh) if ((t) < NTILE) {                              \
    gload16(bP[0] + (t) * 64 + (kh) * 32, &sB[s][wv * 512]);          \
    if (GB == 2) gload16(bP[1] + (t) * 64 + (kh) * 32, &sB[s][4096 + wv * 512]); }
#define WAITV if (GB == 2) asm volatile("s_waitcnt vmcnt(4)" ::: "memory"); \
              else         asm volatile("s_waitcnt vmcnt(3)" ::: "memory");

  bfx8 af[4], bf[NR];

#define PH(s, h, STG, W)                                                        \
  {                                                                             \
    if ((h) == 0) {                                                             \
      _Pragma("unroll")                                                         \
      for (int j = 0; j < NR; ++j)                                              \
        bf[j] = *(const bfx8*)&sB[s][(wn * (BN / 4) + j * 16 + lr) * 32 + lg * 8]; \
    }                                                                           \
    _Pragma("unroll")                                                           \
    for (int i = 0; i < 4; ++i)                                                 \
      af[i] = *(const bfx8*)&sA[s][(wm * 128 + (h) * 64 + i * 16 + lr) * 32 + lg * 8]; \
    STG                                                                         \
    asm volatile("s_barrier" ::: "memory");                                     \
    __builtin_amdgcn_s_setprio(1);                                              \
    _Pragma("unroll")                                                           \
    for (int i = 0; i < 4; ++i)                                                 \
      _Pragma("unroll")                                                         \
      for (int j = 0; j < NR; ++j)                                              \
        acc[(h) * 4 + i][j] = __builtin_amdgcn_mfma_f32_16x16x32_bf16(          \
            af[i], bf[j], acc[(h) * 4 + i][j], 0, 0, 0);                        \
    __builtin_amdgcn_s_setprio(0);                                              \
    if (W) { WAITV }                                                            \
    asm volatile("s_barrier" ::: "memory");                                     \
  }

  // prologue: slots 0,1 = tile0 kh0/kh1; slot 2 = tile1 kh0
  SGA(0, 0, 0) SGB(0, 0, 0)
  SGA(1, 0, 1) SGB(1, 0, 1)
  SGA(2, 1, 0) SGB(2, 1, 0)
  WAITV
  asm volatile("s_barrier" ::: "memory");

  for (int it = 0; it < NTILE / 2; ++it) {
    const int t = 2 * it;
    PH(0, 0, SGA(3, t + 1, 1), 0)
    PH(0, 1, SGB(3, t + 1, 1), 0)
    PH(1, 0, SGA(0, t + 2, 0), 0)
    PH(1, 1, SGB(0, t + 2, 0), 1)
    PH(2, 0, SGA(1, t + 2, 1), 0)
    PH(2, 1, SGB(1, t + 2, 1), 0)
    PH(3, 0, SGA(2, t + 3, 0), 0)
    PH(3, 1, SGB(2, t + 3, 0), 1)
  }
#undef PH
#undef SGA
#undef SGB
#undef WAITV

  if constexpr (FIRST) {
#pragma unroll
    for (int mi = 0; mi < 8; ++mi) {
#pragma unroll
      for (int r = 0; r < 4; ++r) {
        const int row = wm * 128 + (mi >> 2) * 64 + (mi & 3) * 16 + lg * 4 + r;
        if (m0 + row >= cnt) continue;
        unsigned short* hrow = Hout + (size_t)(rbase + m0 + row) * N;
#pragma unroll
        for (int j = 0; j < NR; ++j) {
          const int col = n0 + wn * (BN / 4) + j * 16 + lr;
          float v = acc[mi][j][r] + bias[e * N + col];
          hrow[col] = f2bf(v > 0.f ? v : 0.f);
        }
      }
    }
  } else {
#pragma unroll
    for (int mi = 0; mi < 8; ++mi) {
#pragma unroll
      for (int r = 0; r < 4; ++r) {
        const int row = wm * 128 + (mi >> 2) * 64 + (mi & 3) * 16 + lg * 4 + r;
        if (m0 + row >= cnt) continue;
        const int tok = row_tok[rbase + m0 + row];
        const float al = alpha[tok];
        const float* xrow = xin + (size_t)tok * N;
        float* orow = out + (size_t)tok * N;
#pragma unroll
        for (int j = 0; j < NR; ++j) {
          const int col = n0 + wn * (BN / 4) + j * 16 + lr;
          orow[col] = xrow[col] + al * (acc[mi][j][r] + bias[e * N + col]);
        }
      }
    }
  }
}

extern "C" void kernel_launch(void* const* d_in, const int* in_sizes, int n_in,
                              void* d_out, int out_size, void* d_ws, size_t ws_size,
                              hipStream_t stream)
{
  const float* x    = (const float*)d_in[0];
  const float* cent = (const float*)d_in[1];
  const float* ln_g = (const float*)d_in[2];
  const float* ln_b = (const float*)d_in[3];
  const float* w1   = (const float*)d_in[4];
  const float* b1   = (const float*)d_in[5];
  const float* w2   = (const float*)d_in[6];
  const float* b2   = (const float*)d_in[7];
  float* out = (float*)d_out;

  char* ws = (char*)d_ws;
  unsigned short* xln  = (unsigned short*)(ws);                          // 16 MB [NT][DIM] bf16
  unsigned short* hbuf = (unsigned short*)(ws + (16ull << 20));          // 64 MB [NT][FDIM] bf16
  unsigned short* w1t  = (unsigned short*)(ws + (80ull << 20));          // 64 MB [E][F][D] bf16
  unsigned short* w2t  = (unsigned short*)(ws + (144ull << 20));         // 64 MB [E][D][F] bf16
  char* tail = ws + (208ull << 20);
  int*   eid    = (int*)(tail);
  float* alpha  = (float*)(tail + 32768);
  int*   rowtok = (int*)(tail + 65536);
  int*   counts = (int*)(tail + 98304);
  int*   basep  = counts + 16;
  int*   cur    = counts + 32;

  k_zero<<<1, 64, 0, stream>>>(counts);
  k_routing<<<NT, 256, 0, stream>>>(x, cent, eid, alpha, counts);
  k_scan<<<1, 1, 0, stream>>>(counts, basep, cur);
  k_ln_scatter<<<NT, 256, 0, stream>>>(x, ln_g, ln_b, eid, cur, rowtok, xln);
  k_transpose<<<dim3(FDIM / 64, DIM / 64, NEXP), 256, 0, stream>>>(w1, w1t, DIM, FDIM);
  k_transpose<<<dim3(DIM / 64, FDIM / 64, NEXP), 256, 0, stream>>>(w2, w2t, FDIM, DIM);
  k_gemm<DIM, FDIM, 256, true><<<NEXP * (NT / 256) * (FDIM / 256), 512, 0, stream>>>(
      xln, w1t, b1, basep, counts, hbuf, nullptr, nullptr, nullptr, nullptr);
  k_gemm<FDIM, DIM, 128, false><<<NEXP * (NT / 256) * (DIM / 128), 512, 0, stream>>>(
      hbuf, w2t, b2, basep, counts, nullptr, rowtok, alpha, x, out);
}

// Round 6
// 625.594 us; speedup vs baseline: 1.1260x; 1.1260x over previous
//
#include <hip/hip_runtime.h>

#define NT 8192      // tokens = B*S
#define DIM 1024     // D
#define FDIM 4096    // F
#define NEXP 8       // experts

typedef __attribute__((ext_vector_type(8))) short bfx8;   // 8 bf16 (4 VGPRs)
typedef __attribute__((ext_vector_type(4))) float fx4;    // MFMA accumulator

__device__ __forceinline__ unsigned short f2bf(float f) {
  union { float f; unsigned u; } v; v.f = f;
  unsigned u = v.u;
  unsigned r = u + 0x7FFFu + ((u >> 16) & 1u);   // round-to-nearest-even
  return (unsigned short)(r >> 16);
}

__device__ __forceinline__ void gload16(const void* g, void* l) {
  __builtin_amdgcn_global_load_lds(
      (const __attribute__((address_space(1))) unsigned int*)g,
      (__attribute__((address_space(3))) unsigned int*)l, 16, 0, 0);
}

// ---------------- zero counters ----------------
__global__ void k_zero(int* __restrict__ counts) {
  if (threadIdx.x < NEXP) counts[threadIdx.x] = 0;
}

// ---------------- routing: argmax affinity + alpha ----------------
__global__ __launch_bounds__(256) void k_routing(
    const float* __restrict__ x, const float* __restrict__ cent,
    int* __restrict__ eid, float* __restrict__ alpha, int* __restrict__ counts)
{
  const int t = blockIdx.x, tid = threadIdx.x;
  const float4 xv = ((const float4*)(x + (size_t)t * DIM))[tid];
  float acc[NEXP];
#pragma unroll
  for (int e = 0; e < NEXP; ++e) {
    const float4 cv = ((const float4*)(cent + (size_t)e * DIM))[tid];
    acc[e] = xv.x * cv.x + xv.y * cv.y + xv.z * cv.z + xv.w * cv.w;
  }
#pragma unroll
  for (int off = 32; off > 0; off >>= 1)
#pragma unroll
    for (int e = 0; e < NEXP; ++e) acc[e] += __shfl_down(acc[e], off);
  __shared__ float part[4][NEXP];
  const int lane = tid & 63, w = tid >> 6;
  if (lane == 0)
#pragma unroll
    for (int e = 0; e < NEXP; ++e) part[w][e] = acc[e];
  __syncthreads();
  if (tid == 0) {
    int best = 0; float bv = -1e30f;
#pragma unroll
    for (int e = 0; e < NEXP; ++e) {
      float v = part[0][e] + part[1][e] + part[2][e] + part[3][e];
      if (v > bv) { bv = v; best = e; }
    }
    eid[t] = best;
    alpha[t] = 1.0f / (1.0f + expf(-bv));
    atomicAdd(&counts[best], 1);
  }
}

// ---------------- exclusive scan of 8 counts ----------------
__global__ void k_scan(const int* __restrict__ counts, int* __restrict__ bs, int* __restrict__ cur) {
  if (threadIdx.x == 0) {
    int s = 0;
    for (int e = 0; e < NEXP; ++e) { bs[e] = s; cur[e] = s; s += counts[e]; }
  }
}

// ---------------- LayerNorm + counting-sort scatter (bf16) ----------------
__global__ __launch_bounds__(256) void k_ln_scatter(
    const float* __restrict__ x, const float* __restrict__ g, const float* __restrict__ b,
    const int* __restrict__ eid, int* __restrict__ cur,
    int* __restrict__ row_tok, unsigned short* __restrict__ xln)
{
  const int t = blockIdx.x, tid = threadIdx.x;
  const float4 xv = ((const float4*)(x + (size_t)t * DIM))[tid];
  float s = xv.x + xv.y + xv.z + xv.w;
  float ss = xv.x * xv.x + xv.y * xv.y + xv.z * xv.z + xv.w * xv.w;
#pragma unroll
  for (int off = 32; off > 0; off >>= 1) { s += __shfl_down(s, off); ss += __shfl_down(ss, off); }
  __shared__ float ps[4], pss[4];
  __shared__ float smu, srstd;
  __shared__ int spos, se;
  const int lane = tid & 63, w = tid >> 6;
  if (lane == 0) { ps[w] = s; pss[w] = ss; }
  __syncthreads();
  if (tid == 0) {
    const float sum = ps[0] + ps[1] + ps[2] + ps[3];
    const float sq  = pss[0] + pss[1] + pss[2] + pss[3];
    const float mu = sum * (1.0f / DIM);
    const float var = sq * (1.0f / DIM) - mu * mu;
    smu = mu; srstd = rsqrtf(var + 1e-5f);
    const int e = eid[t]; se = e;
    const int pos = atomicAdd(&cur[e], 1);
    row_tok[pos] = t;
    spos = pos;
  }
  __syncthreads();
  const float mu = smu, rstd = srstd;
  const int e = se, pos = spos;
  const float4 gv = ((const float4*)(g + (size_t)e * DIM))[tid];
  const float4 bv = ((const float4*)(b + (size_t)e * DIM))[tid];
  ushort4 o;
  o.x = f2bf((xv.x - mu) * rstd * gv.x + bv.x);
  o.y = f2bf((xv.y - mu) * rstd * gv.y + bv.y);
  o.z = f2bf((xv.z - mu) * rstd * gv.z + bv.z);
  o.w = f2bf((xv.w - mu) * rstd * gv.w + bv.w);
  ((ushort4*)(xln + (size_t)pos * DIM))[tid] = o;
}

// ---------------- transpose fp32 [R][C] -> bf16 [C][R], 64x64 tiles ----------------
__global__ __launch_bounds__(256) void k_transpose(
    const float* __restrict__ in, unsigned short* __restrict__ outT, int R, int C)
{
  __shared__ float T[64 * 65];
  const int e = blockIdx.z;
  const float* src = in + (size_t)e * R * C;
  unsigned short* dst = outT + (size_t)e * R * C;
  const int r0 = blockIdx.y * 64, c0 = blockIdx.x * 64;
  const int t = threadIdx.x;
  const int ry = t >> 4, c4 = (t & 15) * 4;
#pragma unroll
  for (int i = 0; i < 4; ++i) {
    const int r = ry + i * 16;
    const float4 v = *(const float4*)(src + (size_t)(r0 + r) * C + c0 + c4);
    T[r * 65 + c4 + 0] = v.x;
    T[r * 65 + c4 + 1] = v.y;
    T[r * 65 + c4 + 2] = v.z;
    T[r * 65 + c4 + 3] = v.w;
  }
  __syncthreads();
  const int q = t & 7, ny = t >> 3;
#pragma unroll
  for (int i = 0; i < 2; ++i) {
    const int n = ny + i * 32;
    unsigned short o[8];
#pragma unroll
    for (int u = 0; u < 8; ++u) o[u] = f2bf(T[(q * 8 + u) * 65 + n]);
    *(uint4*)(dst + (size_t)(c0 + n) * R + r0 + q * 8) = *(const uint4*)o;
  }
}

// ---------------- grouped MFMA GEMM, 128x128 tile, BK=64, 4 waves ----------------
// R4's proven single-buffer 2-barrier loop, but BK=64: half the vmcnt(0)
// drains per FLOP (32 MFMA per barrier pair). 128B LDS rows would be a
// 16-way read conflict, so: linear gload_lds dest + INVERSE-swizzled global
// source + swizzled ds_read (slot ^= row&7 on 16B slots; involution).
// Grid 1D: expert = bid&7 (== XCD), n-panel, m fastest (weights L2-resident).
template<int K, int N, bool FIRST>
__global__ __launch_bounds__(256) void k_gemm(
    const unsigned short* __restrict__ A,
    const unsigned short* __restrict__ Bt,
    const float* __restrict__ bias,
    const int* __restrict__ bs, const int* __restrict__ counts,
    unsigned short* __restrict__ Hout,
    const int* __restrict__ row_tok, const float* __restrict__ alpha,
    const float* __restrict__ xin, float* __restrict__ out)
{
  const int MB = NT / 128;
  const int bid = blockIdx.x;
  const int e = bid & 7;
  const int l = bid >> 3;
  const int m0 = (l % MB) * 128;               // m fastest
  const int n0 = (l / MB) * 128;

  const int cnt = counts[e];
  if (m0 >= cnt) return;
  const int rbase = bs[e];

  __shared__ unsigned short lA[128 * 64];   // linear dest (global_load_lds)
  __shared__ unsigned short lB[128 * 64];

  const int tid = threadIdx.x;
  const int lane = tid & 63, wv = tid >> 6;
  const int wm = (wv >> 1) * 64, wn = (wv & 1) * 64;
  const int lr = lane & 15, lg = lane >> 4;

  fx4 acc[4][4] = {};

  const unsigned short* Bte = Bt + (size_t)e * N * K;

  // staging: chunk c = p*256+tid -> tile row c>>3, physical 16B slot c&7.
  // source k-slot = (c&7) ^ (row&7)  (pre-swizzle so swizzled read is linear-free)
  const unsigned short* aP[4];
  const unsigned short* bP[4];
#pragma unroll
  for (int p = 0; p < 4; ++p) {
    const int c = p * 256 + tid;
    const int row = c >> 3;
    const int kq = ((c & 7) ^ (row & 7)) * 8;
    int ar = rbase + m0 + row;
    ar = ar < NT ? ar : NT - 1;               // clamp: pad rows masked at epilogue
    aP[p] = A + (size_t)ar * K + kq;
    bP[p] = Bte + (size_t)(n0 + row) * K + kq;
  }

  for (int k0 = 0; k0 < K; k0 += 64) {
#pragma unroll
    for (int p = 0; p < 4; ++p)
      gload16(aP[p] + k0, &lA[p * 2048 + wv * 512]);
#pragma unroll
    for (int p = 0; p < 4; ++p)
      gload16(bP[p] + k0, &lB[p * 2048 + wv * 512]);
    __syncthreads();                          // compiler-managed vmcnt drain
#pragma unroll
    for (int kk = 0; kk < 2; ++kk) {
      bfx8 af[4], bf[4];
#pragma unroll
      for (int i = 0; i < 4; ++i) {
        const int R = wm + i * 16 + lr;
        af[i] = *(const bfx8*)&lA[R * 64 + ((((kk << 2) + lg) ^ (R & 7)) << 3)];
      }
#pragma unroll
      for (int j = 0; j < 4; ++j) {
        const int R = wn + j * 16 + lr;
        bf[j] = *(const bfx8*)&lB[R * 64 + ((((kk << 2) + lg) ^ (R & 7)) << 3)];
      }
#pragma unroll
      for (int i = 0; i < 4; ++i)
#pragma unroll
        for (int j = 0; j < 4; ++j)
          acc[i][j] = __builtin_amdgcn_mfma_f32_16x16x32_bf16(af[i], bf[j], acc[i][j], 0, 0, 0);
    }
    __syncthreads();
  }

  if constexpr (FIRST) {
#pragma unroll
    for (int i = 0; i < 4; ++i) {
#pragma unroll
      for (int r2 = 0; r2 < 4; ++r2) {
        const int rl = wm + i * 16 + lg * 4 + r2;
        if (m0 + rl >= cnt) continue;
        unsigned short* hrow = Hout + (size_t)(rbase + m0 + rl) * N;
#pragma unroll
        for (int j = 0; j < 4; ++j) {
          const int col = n0 + wn + j * 16 + lr;
          float v = acc[i][j][r2] + bias[e * N + col];
          hrow[col] = f2bf(v > 0.f ? v : 0.f);
        }
      }
    }
  } else {
#pragma unroll
    for (int i = 0; i < 4; ++i) {
#pragma unroll
      for (int r2 = 0; r2 < 4; ++r2) {
        const int rl = wm + i * 16 + lg * 4 + r2;
        if (m0 + rl >= cnt) continue;
        const int tok = row_tok[rbase + m0 + rl];
        const float al = alpha[tok];
        const float* xrow = xin + (size_t)tok * N;
        float* orow = out + (size_t)tok * N;
#pragma unroll
        for (int j = 0; j < 4; ++j) {
          const int col = n0 + wn + j * 16 + lr;
          orow[col] = xrow[col] + al * (acc[i][j][r2] + bias[e * N + col]);
        }
      }
    }
  }
}

extern "C" void kernel_launch(void* const* d_in, const int* in_sizes, int n_in,
                              void* d_out, int out_size, void* d_ws, size_t ws_size,
                              hipStream_t stream)
{
  const float* x    = (const float*)d_in[0];
  const float* cent = (const float*)d_in[1];
  const float* ln_g = (const float*)d_in[2];
  const float* ln_b = (const float*)d_in[3];
  const float* w1   = (const float*)d_in[4];
  const float* b1   = (const float*)d_in[5];
  const float* w2   = (const float*)d_in[6];
  const float* b2   = (const float*)d_in[7];
  float* out = (float*)d_out;

  char* ws = (char*)d_ws;
  unsigned short* xln  = (unsigned short*)(ws);                          // 16 MB [NT][DIM] bf16
  unsigned short* hbuf = (unsigned short*)(ws + (16ull << 20));          // 64 MB [NT][FDIM] bf16
  unsigned short* w1t  = (unsigned short*)(ws + (80ull << 20));          // 64 MB [E][F][D] bf16
  unsigned short* w2t  = (unsigned short*)(ws + (144ull << 20));         // 64 MB [E][D][F] bf16
  char* tail = ws + (208ull << 20);
  int*   eid    = (int*)(tail);
  float* alpha  = (float*)(tail + 32768);
  int*   rowtok = (int*)(tail + 65536);
  int*   counts = (int*)(tail + 98304);
  int*   basep  = counts + 16;
  int*   cur    = counts + 32;

  k_zero<<<1, 64, 0, stream>>>(counts);
  k_routing<<<NT, 256, 0, stream>>>(x, cent, eid, alpha, counts);
  k_scan<<<1, 1, 0, stream>>>(counts, basep, cur);
  k_ln_scatter<<<NT, 256, 0, stream>>>(x, ln_g, ln_b, eid, cur, rowtok, xln);
  k_transpose<<<dim3(FDIM / 64, DIM / 64, NEXP), 256, 0, stream>>>(w1, w1t, DIM, FDIM);
  k_transpose<<<dim3(DIM / 64, FDIM / 64, NEXP), 256, 0, stream>>>(w2, w2t, FDIM, DIM);
  k_gemm<DIM, FDIM, true><<<NEXP * (NT / 128) * (FDIM / 128), 256, 0, stream>>>(
      xln, w1t, b1, basep, counts, hbuf, nullptr, nullptr, nullptr, nullptr);
  k_gemm<FDIM, DIM, false><<<NEXP * (NT / 128) * (DIM / 128), 256, 0, stream>>>(
      hbuf, w2t, b2, basep, counts, nullptr, rowtok, alpha, x, out);
}

// Round 7
// 529.816 us; speedup vs baseline: 1.3296x; 1.1808x over previous
//
#include <hip/hip_runtime.h>

#define NT 8192      // tokens = B*S
#define DIM 1024     // D
#define FDIM 4096    // F
#define NEXP 8       // experts

typedef __attribute__((ext_vector_type(8))) short bfx8;   // 8 bf16 (4 VGPRs)
typedef __attribute__((ext_vector_type(4))) float fx4;    // MFMA accumulator

__device__ __forceinline__ unsigned short f2bf(float f) {
  union { float f; unsigned u; } v; v.f = f;
  unsigned u = v.u;
  unsigned r = u + 0x7FFFu + ((u >> 16) & 1u);   // round-to-nearest-even
  return (unsigned short)(r >> 16);
}

__device__ __forceinline__ void gload16(const void* g, void* l) {
  __builtin_amdgcn_global_load_lds(
      (const __attribute__((address_space(1))) unsigned int*)g,
      (__attribute__((address_space(3))) unsigned int*)l, 16, 0, 0);
}

// ---------------- zero counters ----------------
__global__ void k_zero(int* __restrict__ counts) {
  if (threadIdx.x < NEXP) counts[threadIdx.x] = 0;
}

// ---------------- shared transpose tile helper (fp32 [R][C] -> bf16 [C][R]) ----------------
__device__ __forceinline__ void transpose_tile(
    const float* __restrict__ src, unsigned short* __restrict__ dst,
    int R, int C, int r0, int c0, float* T, int t)
{
  const int ry = t >> 4, c4 = (t & 15) * 4;
#pragma unroll
  for (int i = 0; i < 4; ++i) {
    const int r = ry + i * 16;
    const float4 v = *(const float4*)(src + (size_t)(r0 + r) * C + c0 + c4);
    T[r * 65 + c4 + 0] = v.x;
    T[r * 65 + c4 + 1] = v.y;
    T[r * 65 + c4 + 2] = v.z;
    T[r * 65 + c4 + 3] = v.w;
  }
  __syncthreads();
  const int q = t & 7, ny = t >> 3;
#pragma unroll
  for (int i = 0; i < 2; ++i) {
    const int n = ny + i * 32;
    unsigned short o[8];
#pragma unroll
    for (int u = 0; u < 8; ++u) o[u] = f2bf(T[(q * 8 + u) * 65 + n]);
    *(uint4*)(dst + (size_t)(c0 + n) * R + r0 + q * 8) = *(const uint4*)o;
  }
}

// ---------------- fused pre-pass: routing+LN-stats | w1 transpose | w2 transpose ----------------
// blocks [0,NT): routing + LN stats; [NT,NT+8192): w1t tiles; [NT+8192,NT+16384): w2t tiles.
__global__ __launch_bounds__(256) void k_pre(
    const float* __restrict__ x, const float* __restrict__ cent,
    const float* __restrict__ w1, const float* __restrict__ w2,
    int* __restrict__ eid, float* __restrict__ alpha, float2* __restrict__ stats,
    int* __restrict__ counts,
    unsigned short* __restrict__ w1t, unsigned short* __restrict__ w2t)
{
  __shared__ float T[64 * 65];
  __shared__ float part[4][NEXP];
  __shared__ float ps[4], pss[4];
  const int bid = blockIdx.x;
  const int tid = threadIdx.x;

  if (bid < NT) {
    const int t = bid;
    const float4 xv = ((const float4*)(x + (size_t)t * DIM))[tid];
    float acc[NEXP];
#pragma unroll
    for (int e = 0; e < NEXP; ++e) {
      const float4 cv = ((const float4*)(cent + (size_t)e * DIM))[tid];
      acc[e] = xv.x * cv.x + xv.y * cv.y + xv.z * cv.z + xv.w * cv.w;
    }
    float s = xv.x + xv.y + xv.z + xv.w;
    float ss = xv.x * xv.x + xv.y * xv.y + xv.z * xv.z + xv.w * xv.w;
#pragma unroll
    for (int off = 32; off > 0; off >>= 1) {
#pragma unroll
      for (int e = 0; e < NEXP; ++e) acc[e] += __shfl_down(acc[e], off);
      s += __shfl_down(s, off); ss += __shfl_down(ss, off);
    }
    const int lane = tid & 63, w = tid >> 6;
    if (lane == 0) {
#pragma unroll
      for (int e = 0; e < NEXP; ++e) part[w][e] = acc[e];
      ps[w] = s; pss[w] = ss;
    }
    __syncthreads();
    if (tid == 0) {
      int best = 0; float bv = -1e30f;
#pragma unroll
      for (int e = 0; e < NEXP; ++e) {
        float v = part[0][e] + part[1][e] + part[2][e] + part[3][e];
        if (v > bv) { bv = v; best = e; }   // strict >: first max (matches argmax)
      }
      eid[t] = best;
      alpha[t] = 1.0f / (1.0f + expf(-bv));
      atomicAdd(&counts[best], 1);
      const float sum = ps[0] + ps[1] + ps[2] + ps[3];
      const float sq  = pss[0] + pss[1] + pss[2] + pss[3];
      const float mu = sum * (1.0f / DIM);
      const float var = sq * (1.0f / DIM) - mu * mu;
      stats[t] = make_float2(mu, rsqrtf(var + 1e-5f));
    }
  } else if (bid < NT + NEXP * 1024) {
    const int i = bid - NT;
    const int e = i >> 10, rem = i & 1023;          // 64 cols x 16 rows
    transpose_tile(w1 + (size_t)e * DIM * FDIM, w1t + (size_t)e * DIM * FDIM,
                   DIM, FDIM, (rem >> 6) * 64, (rem & 63) * 64, T, tid);
  } else {
    const int i = bid - NT - NEXP * 1024;
    const int e = i >> 10, rem = i & 1023;          // 16 cols x 64 rows
    transpose_tile(w2 + (size_t)e * FDIM * DIM, w2t + (size_t)e * FDIM * DIM,
                   FDIM, DIM, (rem >> 4) * 64, (rem & 15) * 64, T, tid);
  }
}

// ---------------- exclusive scan of 8 counts ----------------
__global__ void k_scan(const int* __restrict__ counts, int* __restrict__ bs, int* __restrict__ cur) {
  if (threadIdx.x == 0) {
    int s = 0;
    for (int e = 0; e < NEXP; ++e) { bs[e] = s; cur[e] = s; s += counts[e]; }
  }
}

// ---------------- LayerNorm apply + counting-sort scatter (bf16) ----------------
__global__ __launch_bounds__(256) void k_ln_scatter(
    const float* __restrict__ x, const float* __restrict__ g, const float* __restrict__ b,
    const int* __restrict__ eid, const float2* __restrict__ stats, int* __restrict__ cur,
    int* __restrict__ row_tok, unsigned short* __restrict__ xln)
{
  const int t = blockIdx.x, tid = threadIdx.x;
  __shared__ int spos;
  const int e = eid[t];
  if (tid == 0) {
    const int pos = atomicAdd(&cur[e], 1);
    row_tok[pos] = t;
    spos = pos;
  }
  const float4 xv = ((const float4*)(x + (size_t)t * DIM))[tid];
  const float2 st = stats[t];
  const float mu = st.x, rstd = st.y;
  const float4 gv = ((const float4*)(g + (size_t)e * DIM))[tid];
  const float4 bv = ((const float4*)(b + (size_t)e * DIM))[tid];
  __syncthreads();
  const int pos = spos;
  ushort4 o;
  o.x = f2bf((xv.x - mu) * rstd * gv.x + bv.x);
  o.y = f2bf((xv.y - mu) * rstd * gv.y + bv.y);
  o.z = f2bf((xv.z - mu) * rstd * gv.z + bv.z);
  o.w = f2bf((xv.w - mu) * rstd * gv.w + bv.w);
  ((ushort4*)(xln + (size_t)pos * DIM))[tid] = o;
}

// ---------------- grouped MFMA GEMM, 128x128 tile, BK=32, 4 waves ----------------
// R4-proven shell; __launch_bounds__(256,4) caps unified regs at 128 so blocks/CU
// doubles past the 128-reg HW tier (m69). Inner loop keeps only bf[4]+one af live.
// Grid 1D: expert = bid&7 (== XCD), n-panel, m fastest (weights L2-resident).
template<int K, int N, bool FIRST>
__global__ __launch_bounds__(256, 4) void k_gemm(
    const unsigned short* __restrict__ A,
    const unsigned short* __restrict__ Bt,
    const float* __restrict__ bias,
    const int* __restrict__ bs, const int* __restrict__ counts,
    unsigned short* __restrict__ Hout,
    const int* __restrict__ row_tok, const float* __restrict__ alpha,
    const float* __restrict__ xin, float* __restrict__ out)
{
  const int MB = NT / 128;
  const int bid = blockIdx.x;
  const int e = bid & 7;
  const int l = bid >> 3;
  const int m0 = (l % MB) * 128;               // m fastest
  if (m0 >= counts[e]) return;
  const int cnt = counts[e];
  const int n0 = (l / MB) * 128;
  const int rbase = bs[e];

  __shared__ unsigned short lA[128 * 32];   // linear (global_load_lds dest)
  __shared__ unsigned short lB[128 * 32];

  const int tid = threadIdx.x;
  const int lane = tid & 63, wv = tid >> 6;
  const int wm = (wv >> 1) * 64, wn = (wv & 1) * 64;
  const int lr = lane & 15, lg = lane >> 4;

  fx4 acc[4][4] = {};

  const unsigned short* Bte = Bt + (size_t)e * N * K;

  // staging: chunk g = p*256+tid -> row g>>2, k-off (g&3)*8;
  // LDS linear elem offset 8*g = wave-uniform (p*4+wv)*512 + lane*8.
  const unsigned short* aP[2];
  const unsigned short* bP[2];
#pragma unroll
  for (int p = 0; p < 2; ++p) {
    const int g = p * 256 + tid;
    const int row = g >> 2, kq = (g & 3) * 8;
    int ar = rbase + m0 + row;
    ar = ar < NT ? ar : NT - 1;               // clamp: pad rows masked at epilogue
    aP[p] = A + (size_t)ar * K + kq;
    bP[p] = Bte + (size_t)(n0 + row) * K + kq;
  }

  for (int k0 = 0; k0 < K; k0 += 32) {
    gload16(aP[0] + k0, &lA[(0 * 4 + wv) * 512]);
    gload16(aP[1] + k0, &lA[(1 * 4 + wv) * 512]);
    gload16(bP[0] + k0, &lB[(0 * 4 + wv) * 512]);
    gload16(bP[1] + k0, &lB[(1 * 4 + wv) * 512]);
    __syncthreads();                          // compiler-managed vmcnt drain
    bfx8 bf[4];
#pragma unroll
    for (int j = 0; j < 4; ++j)
      bf[j] = *(const bfx8*)(&lB[(wn + j * 16 + lr) * 32 + lg * 8]);
#pragma unroll
    for (int i = 0; i < 4; ++i) {
      const bfx8 af = *(const bfx8*)(&lA[(wm + i * 16 + lr) * 32 + lg * 8]);
#pragma unroll
      for (int j = 0; j < 4; ++j)
        acc[i][j] = __builtin_amdgcn_mfma_f32_16x16x32_bf16(af, bf[j], acc[i][j], 0, 0, 0);
    }
    __syncthreads();
  }

  const float* be = bias + (size_t)e * N;
  if constexpr (FIRST) {
#pragma unroll
    for (int i = 0; i < 4; ++i) {
#pragma unroll
      for (int r2 = 0; r2 < 4; ++r2) {
        const int rl = wm + i * 16 + lg * 4 + r2;
        if (m0 + rl >= cnt) continue;
        unsigned short* hrow = Hout + (size_t)(rbase + m0 + rl) * N;
#pragma unroll
        for (int j = 0; j < 4; ++j) {
          const int col = n0 + wn + j * 16 + lr;
          float v = acc[i][j][r2] + be[col];
          hrow[col] = f2bf(v > 0.f ? v : 0.f);
        }
      }
    }
  } else {
#pragma unroll
    for (int i = 0; i < 4; ++i) {
#pragma unroll
      for (int r2 = 0; r2 < 4; ++r2) {
        const int rl = wm + i * 16 + lg * 4 + r2;
        if (m0 + rl >= cnt) continue;
        const int tok = row_tok[rbase + m0 + rl];
        const float al = alpha[tok];
        const float* xrow = xin + (size_t)tok * N;
        float* orow = out + (size_t)tok * N;
#pragma unroll
        for (int j = 0; j < 4; ++j) {
          const int col = n0 + wn + j * 16 + lr;
          orow[col] = xrow[col] + al * (acc[i][j][r2] + be[col]);
        }
      }
    }
  }
}

extern "C" void kernel_launch(void* const* d_in, const int* in_sizes, int n_in,
                              void* d_out, int out_size, void* d_ws, size_t ws_size,
                              hipStream_t stream)
{
  const float* x    = (const float*)d_in[0];
  const float* cent = (const float*)d_in[1];
  const float* ln_g = (const float*)d_in[2];
  const float* ln_b = (const float*)d_in[3];
  const float* w1   = (const float*)d_in[4];
  const float* b1   = (const float*)d_in[5];
  const float* w2   = (const float*)d_in[6];
  const float* b2   = (const float*)d_in[7];
  float* out = (float*)d_out;

  char* ws = (char*)d_ws;
  unsigned short* xln  = (unsigned short*)(ws);                          // 16 MB [NT][DIM] bf16
  unsigned short* hbuf = (unsigned short*)(ws + (16ull << 20));          // 64 MB [NT][FDIM] bf16
  unsigned short* w1t  = (unsigned short*)(ws + (80ull << 20));          // 64 MB [E][F][D] bf16
  unsigned short* w2t  = (unsigned short*)(ws + (144ull << 20));         // 64 MB [E][D][F] bf16
  char* tail = ws + (208ull << 20);
  int*    eid    = (int*)(tail);
  float*  alpha  = (float*)(tail + 32768);
  int*    rowtok = (int*)(tail + 65536);
  int*    counts = (int*)(tail + 98304);
  int*    basep  = counts + 16;
  int*    cur    = counts + 32;
  float2* stats  = (float2*)(tail + 131072);

  k_zero<<<1, 64, 0, stream>>>(counts);
  k_pre<<<NT + 2 * NEXP * 1024, 256, 0, stream>>>(
      x, cent, w1, w2, eid, alpha, stats, counts, w1t, w2t);
  k_scan<<<1, 1, 0, stream>>>(counts, basep, cur);
  k_ln_scatter<<<NT, 256, 0, stream>>>(x, ln_g, ln_b, eid, stats, cur, rowtok, xln);
  k_gemm<DIM, FDIM, true><<<NEXP * (NT / 128) * (FDIM / 128), 256, 0, stream>>>(
      xln, w1t, b1, basep, counts, hbuf, nullptr, nullptr, nullptr, nullptr);
  k_gemm<FDIM, DIM, false><<<NEXP * (NT / 128) * (DIM / 128), 256, 0, stream>>>(
      hbuf, w2t, b2, basep, counts, nullptr, rowtok, alpha, x, out);
}